// Round 5
// baseline (317.773 us; speedup 1.0000x reference)
//
#include <hip/hip_runtime.h>

#define NNODES 100000
#define NMP 3
#define NEDGES 1000000
#define D 64
#define NTOT (NMP * NNODES)          // 300000
#define BINW 1024                    // destination nodes per bin
#define NBIN 293                     // ceil(NTOT / BINW)
#define CAPB 10944                   // slots per bin segment (lambda=10240, +7 sigma)
#define T1 3072                      // edges per split block
#define OVCAP 131072                 // overflow entries (12 B each)

typedef __attribute__((ext_vector_type(8))) short bf16x8;
typedef __attribute__((ext_vector_type(4))) float floatx4;

__device__ __forceinline__ unsigned short f2bf(float f) {
    unsigned u = __float_as_uint(f);
    u = (u + 0x7FFFu + ((u >> 16) & 1u)) >> 16;   // RNE
    return (unsigned short)u;
}
__device__ __forceinline__ float bf2f_lo(unsigned u) { return __uint_as_float(u << 16); }
__device__ __forceinline__ float bf2f_hi(unsigned u) { return __uint_as_float(u & 0xFFFF0000u); }

// ---------------- split: multisplit into 293 bins, direct scatter (no LDS reorder) ----------------
__global__ __launch_bounds__(512) void split_kernel(const int* __restrict__ ei,
                                                    const float* __restrict__ ew,
                                                    int* __restrict__ gcur,
                                                    int* __restrict__ ovcur,
                                                    int* __restrict__ ovf,
                                                    uint2* __restrict__ A) {
    __shared__ int hist[NBIN], cur[NBIN];
    const int t = threadIdx.x;
    const int mp = blockIdx.y;
    const int e0 = blockIdx.x * T1;
    for (int i = t; i < NBIN; i += 512) hist[i] = 0;
    __syncthreads();
    unsigned key[6]; float w[6]; int bn[6];
#pragma unroll
    for (int i = 0; i < 6; ++i) {
        int e = e0 + i * 512 + t;
        bn[i] = -1;
        if (e < NEDGES) {
            int r = ei[(mp * 2 + 0) * NEDGES + e];
            int c = ei[(mp * 2 + 1) * NEDGES + e];
            w[i] = ew[mp * NEDGES + e];
            int cflat = mp * NNODES + c;
            int rflat = mp * NNODES + r;
            int b = cflat >> 10;
            bn[i] = b;
            key[i] = ((unsigned)(cflat & 1023) << 19) | (unsigned)rflat;
            atomicAdd(&hist[b], 1);
        }
    }
    __syncthreads();
    for (int i = t; i < NBIN; i += 512) {
        int v = hist[i];
        cur[i] = v ? atomicAdd(&gcur[i], v) : 0;   // global space reservation -> running cursor
    }
    __syncthreads();
#pragma unroll
    for (int i = 0; i < 6; ++i) {
        if (bn[i] >= 0) {
            int pos = atomicAdd(&cur[bn[i]], 1);
            if (pos < CAPB) {
                A[(size_t)bn[i] * CAPB + pos] = make_uint2(key[i], __float_as_uint(w[i]));
            } else {                               // correctness valve (~never)
                int op = atomicAdd(ovcur, 1);
                if (op < OVCAP) {
                    int cflat = (bn[i] << 10) | (int)(key[i] >> 19);
                    ovf[3 * op] = cflat;
                    ovf[3 * op + 1] = (int)(key[i] & 0x7FFFFu);
                    ovf[3 * op + 2] = __float_as_int(w[i]);
                }
            }
        }
    }
}

// ---------------- compact2: per 1024-node bin -> per-node CSR {rflat, ew}; dinv ----------------
__global__ __launch_bounds__(256) void compact2_kernel(const int* __restrict__ gcur,
                                                       const uint2* __restrict__ A,
                                                       const int* __restrict__ ovcur,
                                                       const int* __restrict__ ovf,
                                                       uint2* __restrict__ C,
                                                       int2* __restrict__ nodeoff,
                                                       float* __restrict__ dinv) {
    const int bin = blockIdx.x;
    __shared__ int cnt[BINW];
    __shared__ float wsum[BINW];
    __shared__ int pos[BINW];
    __shared__ int sh[256];
    const int t = threadIdx.x;
    for (int i = t; i < BINW; i += 256) { cnt[i] = 0; wsum[i] = 0.0f; }
    __syncthreads();
    const int len = min(gcur[bin], CAPB);
    const uint2* Ab = A + (size_t)bin * CAPB;
    for (int p = t; p < len; p += 256) {
        uint2 rec = Ab[p];
        atomicAdd(&cnt[rec.x >> 19], 1);
        atomicAdd(&wsum[rec.x >> 19], __uint_as_float(rec.y));
    }
    const int ovn = min(*ovcur, OVCAP);
    for (int i = t; i < ovn; i += 256) {
        int cflat = ovf[3 * i];
        if ((cflat >> 10) == bin) {
            atomicAdd(&cnt[cflat & 1023], 1);
            atomicAdd(&wsum[cflat & 1023], __int_as_float(ovf[3 * i + 2]));
        }
    }
    __syncthreads();
    // scan: thread t owns nodes 4t..4t+3
    int c0 = cnt[4 * t], c1 = cnt[4 * t + 1], c2 = cnt[4 * t + 2], c3 = cnt[4 * t + 3];
    int vsum = c0 + c1 + c2 + c3;
    sh[t] = vsum;
    __syncthreads();
    for (int d = 1; d < 256; d <<= 1) {
        int add = (t >= d) ? sh[t - d] : 0;
        __syncthreads();
        sh[t] += add;
        __syncthreads();
    }
    const int base = bin * CAPB;
    const int lim = base + CAPB;
    int p0 = base + sh[t] - vsum;
    int p1 = p0 + c0, p2 = p1 + c1, p3 = p2 + c2;
    pos[4 * t] = p0; pos[4 * t + 1] = p1; pos[4 * t + 2] = p2; pos[4 * t + 3] = p3;
    int starts[4] = {p0, p1, p2, p3};
    int cs[4] = {c0, c1, c2, c3};
#pragma unroll
    for (int j = 0; j < 4; ++j) {
        int cl = 4 * t + j;
        int node = (bin << 10) + cl;
        if (node < NTOT) {
            nodeoff[node] = make_int2(starts[j], cs[j]);
            float dg = wsum[cl];
            dinv[node] = (dg > 0.0f) ? rsqrtf(dg) : 0.0f;
        }
    }
    __syncthreads();
    for (int p = t; p < len; p += 256) {
        uint2 rec = Ab[p];
        int s = atomicAdd(&pos[rec.x >> 19], 1);
        if (s < lim) C[s] = make_uint2(rec.x & 0x7FFFFu, rec.y);
    }
    for (int i = t; i < ovn; i += 256) {
        int cflat = ovf[3 * i];
        if ((cflat >> 10) == bin) {
            int s = atomicAdd(&pos[cflat & 1023], 1);
            if (s < lim) C[s] = make_uint2((unsigned)ovf[3 * i + 1], (unsigned)ovf[3 * i + 2]);
        }
    }
}

// ---------------- prep_x: x fp32 [N][64] -> bf16 xb [N][64] (12.8 MB hot gather target) --------
__global__ __launch_bounds__(256) void prep_x_kernel(const float* __restrict__ x,
                                                     unsigned short* __restrict__ xb) {
    int idx = blockIdx.x * 256 + threadIdx.x;          // one thread per 8 elems
    if (idx >= NNODES * D / 8) return;
    const float4* xp = (const float4*)x;
    float4 v0 = xp[idx * 2], v1 = xp[idx * 2 + 1];
    unsigned u0 = (unsigned)f2bf(v0.x) | ((unsigned)f2bf(v0.y) << 16);
    unsigned u1 = (unsigned)f2bf(v0.z) | ((unsigned)f2bf(v0.w) << 16);
    unsigned u2 = (unsigned)f2bf(v1.x) | ((unsigned)f2bf(v1.y) << 16);
    unsigned u3 = (unsigned)f2bf(v1.z) | ((unsigned)f2bf(v1.w) << 16);
    ((uint4*)xb)[idx] = make_uint4(u0, u1, u2, u3);
}

// ---------------- prep: W fp32 [mp][k][n] -> bf16 transposed wT [mp][n][k] ----------------
__global__ __launch_bounds__(256) void prep_w_kernel(const float* __restrict__ W,
                                                     unsigned short* __restrict__ wT) {
    int idx = blockIdx.x * 256 + threadIdx.x;
    if (idx >= NMP * D * D) return;
    int mp = idx >> 12, rem = idx & 4095;
    int k = rem >> 6, n = rem & 63;
    wT[(mp * D + n) * D + k] = f2bf(W[idx]);
}

// ---------------- gather: aggregate x-rows (NOT h) -> agg bf16; dinv_col folded ----------------
// 2 nodes/wave, 4 edge slots/node, depth-2 pipeline. Working set = xb 12.8 MB (L2/L3-hot).
// Per-edge weight = ew * dinv[rflat] (dinv read piggybacks the pipeline, 1.2 MB L2-resident).
__global__ __launch_bounds__(256) void gather_kernel(const int2* __restrict__ nodeoff,
                                                     const uint2* __restrict__ dense,
                                                     const unsigned short* __restrict__ xb,
                                                     const float* __restrict__ dinv,
                                                     unsigned short* __restrict__ agg) {
    const int tid = threadIdx.x;
    const int wave = tid >> 6, lane = tid & 63;
    const int sub = lane >> 5;     // node within wave (0..1)
    const int g = (lane >> 3) & 3; // edge slot (0..3)
    const int f = lane & 7;        // feature chunk (8 bf16 = 16 B)
    const int w = blockIdx.x * 8 + wave * 2 + sub;   // NTOT = 8*37500
    const int base = (w / NNODES) * NNODES;          // mp*NNODES: x-row = rflat - base
    int2 off = nodeoff[w];
    const int start = off.x, end = off.x + off.y;
    const uint4* xp = (const uint4*)xb;
    float acc[8] = {0, 0, 0, 0, 0, 0, 0, 0};
    if (end > start) {
        const int last = end - 1;
        uint2 prA = dense[min(start + g, last)];
        uint2 prB = dense[min(start + 4 + g, last)];
        uint4 hvA = xp[(size_t)(prA.x - base) * 8 + f];
        float dvA = dinv[prA.x];
        for (int p = start; p < end; p += 4) {
            uint2 prC = dense[min(p + 8 + g, last)];
            uint4 hvB = xp[(size_t)(prB.x - base) * 8 + f];   // addr ready 2 rounds ago
            float dvB = dinv[prB.x];
            float wgt = (p + g < end) ? __uint_as_float(prA.y) * dvA : 0.0f;
            acc[0] += wgt * bf2f_lo(hvA.x); acc[1] += wgt * bf2f_hi(hvA.x);
            acc[2] += wgt * bf2f_lo(hvA.y); acc[3] += wgt * bf2f_hi(hvA.y);
            acc[4] += wgt * bf2f_lo(hvA.z); acc[5] += wgt * bf2f_hi(hvA.z);
            acc[6] += wgt * bf2f_lo(hvA.w); acc[7] += wgt * bf2f_hi(hvA.w);
            prA = prB; hvA = hvB; dvA = dvB; prB = prC;
        }
    }
#pragma unroll
    for (int j = 0; j < 8; ++j) {                   // reduce across 4 edge slots
        acc[j] += __shfl_xor(acc[j], 8);
        acc[j] += __shfl_xor(acc[j], 16);
    }
    if (g == 0) {                                   // 8 lanes/node write 128 B contiguous
        float dv = dinv[w];                         // dinv_col folded here (relu after GEMM)
        unsigned u0 = (unsigned)f2bf(acc[0] * dv) | ((unsigned)f2bf(acc[1] * dv) << 16);
        unsigned u1 = (unsigned)f2bf(acc[2] * dv) | ((unsigned)f2bf(acc[3] * dv) << 16);
        unsigned u2 = (unsigned)f2bf(acc[4] * dv) | ((unsigned)f2bf(acc[5] * dv) << 16);
        unsigned u3 = (unsigned)f2bf(acc[6] * dv) | ((unsigned)f2bf(acc[7] * dv) << 16);
        ((uint4*)agg)[(size_t)w * 8 + f] = make_uint4(u0, u1, u2, u3);
    }
}

// ---------------- gemm2: out = relu(agg @ W[mp]) -- streaming MFMA over NTOT rows ----------------
__global__ __launch_bounds__(256) void gemm2_kernel(const unsigned short* __restrict__ agg,
                                                    const unsigned short* __restrict__ wT,
                                                    float* __restrict__ out) {
    const int wave = threadIdx.x >> 6;
    const int lane = threadIdx.x & 63;
    const int rowbase = (blockIdx.x * 4 + wave) * 16;
    if (rowbase >= NTOT) return;
    const int mp = rowbase / NNODES;   // uniform per 16-row tile (NNODES % 16 == 0)
    const int m = lane & 15;
    const int q = lane >> 4;
    const bf16x8* ar = (const bf16x8*)(agg + (size_t)(rowbase + m) * D);
    bf16x8 a0 = ar[q];                 // k = q*8 .. +7
    bf16x8 a1 = ar[4 + q];             // k = 32 + q*8 .. +7
#pragma unroll
    for (int nt = 0; nt < 4; ++nt) {
        const bf16x8* bp = (const bf16x8*)(wT + (size_t)(mp * D + nt * 16 + m) * D);
        bf16x8 b0 = bp[q];
        bf16x8 b1 = bp[4 + q];
        floatx4 acc = {0.f, 0.f, 0.f, 0.f};
        acc = __builtin_amdgcn_mfma_f32_16x16x32_bf16(b0, a0, acc, 0, 0, 0);
        acc = __builtin_amdgcn_mfma_f32_16x16x32_bf16(b1, a1, acc, 0, 0, 0);
        float4 o = make_float4(fmaxf(acc[0], 0.0f), fmaxf(acc[1], 0.0f),
                               fmaxf(acc[2], 0.0f), fmaxf(acc[3], 0.0f));
        *(float4*)(out + (size_t)(rowbase + m) * D + nt * 16 + q * 4) = o;
    }
}

extern "C" void kernel_launch(void* const* d_in, const int* in_sizes, int n_in,
                              void* d_out, int out_size, void* d_ws, size_t ws_size,
                              hipStream_t stream) {
    const float* x  = (const float*)d_in[0];   // [N, 64]
    const float* W  = (const float*)d_in[1];   // [3, 64, 64]
    const int*   ei = (const int*)d_in[2];     // [3, 2, E]
    const float* ew = (const float*)d_in[3];   // [3, E]
    float* out = (float*)d_out;                // [3, N, 64]

    // layout (bytes). A (25.65 MB) dead after compact2; agg (38.4 MB bf16) overlays it.
    char* ws = (char*)d_ws;
    uint2* A           = (uint2*)(ws + 0);                     // 293*10944*8 = 25,652,736 B
    unsigned short* agg= (unsigned short*)(ws + 0);            // 38,400,000 B (overlays A)
    uint2* C           = (uint2*)(ws + 38400000);              // 25,652,736 B
    int2*  nodeoff     = (int2*)(ws + 64052736);               // 2,400,000 B
    float* dinv        = (float*)(ws + 66452736);              // 1,200,000 B
    unsigned short* wT = (unsigned short*)(ws + 67652736);     // 24,576 B
    int*   gcur        = (int*)(ws + 67677312);                // 1,172 B
    int*   ovcur       = (int*)(ws + 67678484);                // 4 B (adjacent to gcur)
    int*   ovf         = (int*)(ws + 67678488);                // 1,572,864 B
    unsigned short* xb = (unsigned short*)(ws + 69251352);     // 12,800,000 B -> ends ~82.05 MB

    hipMemsetAsync(gcur, 0, 1176, stream);     // gcur + ovcur

    split_kernel<<<dim3((NEDGES + T1 - 1) / T1, NMP), 512, 0, stream>>>(ei, ew, gcur,
                                                                        ovcur, ovf, A);
    compact2_kernel<<<NBIN, 256, 0, stream>>>(gcur, A, ovcur, ovf, C, nodeoff, dinv);
    prep_x_kernel<<<(NNODES * D / 8 + 255) / 256, 256, 0, stream>>>(x, xb);
    prep_w_kernel<<<(NMP * D * D + 255) / 256, 256, 0, stream>>>(W, wT);
    gather_kernel<<<NTOT / 8, 256, 0, stream>>>(nodeoff, C, xb, dinv, agg);
    gemm2_kernel<<<(NTOT / 16 + 3) / 4, 256, 0, stream>>>(agg, wT, out);
}

// Round 6
// 284.958 us; speedup vs baseline: 1.1152x; 1.1152x over previous
//
#include <hip/hip_runtime.h>
#include <hip/hip_fp16.h>

#define NNODES 100000
#define NMP 3
#define NEDGES 1000000
#define D 64
#define NTOT (NMP * NNODES)          // 300000
#define BINW 1024                    // destination nodes per bin
#define NBIN 293                     // ceil(NTOT / BINW)
#define CAPB 10944                   // slots per bin segment (lambda=10240, +7 sigma)
#define T1 3072                      // edges per split block
#define OVCAP 131072                 // overflow entries (12 B each)

typedef __attribute__((ext_vector_type(8))) short bf16x8;
typedef __attribute__((ext_vector_type(4))) float floatx4;

__device__ __forceinline__ unsigned short f2bf(float f) {
    unsigned u = __float_as_uint(f);
    u = (u + 0x7FFFu + ((u >> 16) & 1u)) >> 16;   // RNE
    return (unsigned short)u;
}
__device__ __forceinline__ __half2 u2h(unsigned u) {   // bit-cast u32 -> packed half2
    __half2 r;
    *reinterpret_cast<unsigned*>(&r) = u;
    return r;
}

// ---------------- split: multisplit into 293 bins, direct scatter (no LDS reorder) ----------------
__global__ __launch_bounds__(512) void split_kernel(const int* __restrict__ ei,
                                                    const float* __restrict__ ew,
                                                    int* __restrict__ gcur,
                                                    int* __restrict__ ovcur,
                                                    int* __restrict__ ovf,
                                                    uint2* __restrict__ A) {
    __shared__ int hist[NBIN], cur[NBIN];
    const int t = threadIdx.x;
    const int mp = blockIdx.y;
    const int e0 = blockIdx.x * T1;
    for (int i = t; i < NBIN; i += 512) hist[i] = 0;
    __syncthreads();
    unsigned key[6]; float w[6]; int bn[6];
#pragma unroll
    for (int i = 0; i < 6; ++i) {
        int e = e0 + i * 512 + t;
        bn[i] = -1;
        if (e < NEDGES) {
            int r = ei[(mp * 2 + 0) * NEDGES + e];
            int c = ei[(mp * 2 + 1) * NEDGES + e];
            w[i] = ew[mp * NEDGES + e];
            int cflat = mp * NNODES + c;
            int rflat = mp * NNODES + r;
            int b = cflat >> 10;
            bn[i] = b;
            key[i] = ((unsigned)(cflat & 1023) << 19) | (unsigned)rflat;
            atomicAdd(&hist[b], 1);
        }
    }
    __syncthreads();
    for (int i = t; i < NBIN; i += 512) {
        int v = hist[i];
        cur[i] = v ? atomicAdd(&gcur[i], v) : 0;   // global space reservation -> running cursor
    }
    __syncthreads();
#pragma unroll
    for (int i = 0; i < 6; ++i) {
        if (bn[i] >= 0) {
            int pos = atomicAdd(&cur[bn[i]], 1);
            if (pos < CAPB) {
                A[(size_t)bn[i] * CAPB + pos] = make_uint2(key[i], __float_as_uint(w[i]));
            } else {                               // correctness valve (~never)
                int op = atomicAdd(ovcur, 1);
                if (op < OVCAP) {
                    int cflat = (bn[i] << 10) | (int)(key[i] >> 19);
                    ovf[3 * op] = cflat;
                    ovf[3 * op + 1] = (int)(key[i] & 0x7FFFFu);
                    ovf[3 * op + 2] = __float_as_int(w[i]);
                }
            }
        }
    }
}

// ---------------- compact2: per 1024-node bin -> per-node CSR {rflat, ew}; dinv ----------------
__global__ __launch_bounds__(256) void compact2_kernel(const int* __restrict__ gcur,
                                                       const uint2* __restrict__ A,
                                                       const int* __restrict__ ovcur,
                                                       const int* __restrict__ ovf,
                                                       uint2* __restrict__ C,
                                                       int2* __restrict__ nodeoff,
                                                       float* __restrict__ dinv) {
    const int bin = blockIdx.x;
    __shared__ int cnt[BINW];
    __shared__ float wsum[BINW];
    __shared__ int pos[BINW];
    __shared__ int sh[256];
    const int t = threadIdx.x;
    for (int i = t; i < BINW; i += 256) { cnt[i] = 0; wsum[i] = 0.0f; }
    __syncthreads();
    const int len = min(gcur[bin], CAPB);
    const uint2* Ab = A + (size_t)bin * CAPB;
    for (int p = t; p < len; p += 256) {
        uint2 rec = Ab[p];
        atomicAdd(&cnt[rec.x >> 19], 1);
        atomicAdd(&wsum[rec.x >> 19], __uint_as_float(rec.y));
    }
    const int ovn = min(*ovcur, OVCAP);
    for (int i = t; i < ovn; i += 256) {
        int cflat = ovf[3 * i];
        if ((cflat >> 10) == bin) {
            atomicAdd(&cnt[cflat & 1023], 1);
            atomicAdd(&wsum[cflat & 1023], __int_as_float(ovf[3 * i + 2]));
        }
    }
    __syncthreads();
    // scan: thread t owns nodes 4t..4t+3
    int c0 = cnt[4 * t], c1 = cnt[4 * t + 1], c2 = cnt[4 * t + 2], c3 = cnt[4 * t + 3];
    int vsum = c0 + c1 + c2 + c3;
    sh[t] = vsum;
    __syncthreads();
    for (int d = 1; d < 256; d <<= 1) {
        int add = (t >= d) ? sh[t - d] : 0;
        __syncthreads();
        sh[t] += add;
        __syncthreads();
    }
    const int base = bin * CAPB;
    const int lim = base + CAPB;
    int p0 = base + sh[t] - vsum;
    int p1 = p0 + c0, p2 = p1 + c1, p3 = p2 + c2;
    pos[4 * t] = p0; pos[4 * t + 1] = p1; pos[4 * t + 2] = p2; pos[4 * t + 3] = p3;
    int starts[4] = {p0, p1, p2, p3};
    int cs[4] = {c0, c1, c2, c3};
#pragma unroll
    for (int j = 0; j < 4; ++j) {
        int cl = 4 * t + j;
        int node = (bin << 10) + cl;
        if (node < NTOT) {
            nodeoff[node] = make_int2(starts[j], cs[j]);
            float dg = wsum[cl];
            dinv[node] = (dg > 0.0f) ? rsqrtf(dg) : 0.0f;
        }
    }
    __syncthreads();
    for (int p = t; p < len; p += 256) {
        uint2 rec = Ab[p];
        int s = atomicAdd(&pos[rec.x >> 19], 1);
        if (s < lim) C[s] = make_uint2(rec.x & 0x7FFFFu, rec.y);
    }
    for (int i = t; i < ovn; i += 256) {
        int cflat = ovf[3 * i];
        if ((cflat >> 10) == bin) {
            int s = atomicAdd(&pos[cflat & 1023], 1);
            if (s < lim) C[s] = make_uint2((unsigned)ovf[3 * i + 1], (unsigned)ovf[3 * i + 2]);
        }
    }
}

// ---------------- prep: W fp32 [mp][k][n] -> bf16 transposed wT [mp][n][k] ----------------
__global__ __launch_bounds__(256) void prep_w_kernel(const float* __restrict__ W,
                                                     unsigned short* __restrict__ wT) {
    int idx = blockIdx.x * 256 + threadIdx.x;
    if (idx >= NMP * D * D) return;
    int mp = idx >> 12, rem = idx & 4095;
    int k = rem >> 6, n = rem & 63;
    wT[(mp * D + n) * D + k] = f2bf(W[idx]);
}

// ---------------- MFMA GEMM (operand-swapped); h stored as F16 (not bf16) ----------------
// f16 h: 3 more mantissa bits than bf16, enables v_pk_fma_f16 in gather's inner loop.
__global__ __launch_bounds__(256) void gemm_kernel(const float* __restrict__ x,
                                                   const unsigned short* __restrict__ wT,
                                                   const float* __restrict__ dinv,
                                                   unsigned short* __restrict__ h) {
    const int wave = threadIdx.x >> 6;
    const int lane = threadIdx.x & 63;
    const int rowbase = (blockIdx.x * 4 + wave) * 16;
    if (rowbase >= NNODES) return;
    const int m = lane & 15;
    const int q = lane >> 4;
    const float4* xr = (const float4*)(x + (size_t)(rowbase + m) * D);
    bf16x8 a[2];
#pragma unroll
    for (int kc = 0; kc < 2; ++kc) {
        float4 x0 = xr[kc * 8 + q * 2];
        float4 x1 = xr[kc * 8 + q * 2 + 1];
        a[kc][0] = f2bf(x0.x); a[kc][1] = f2bf(x0.y);
        a[kc][2] = f2bf(x0.z); a[kc][3] = f2bf(x0.w);
        a[kc][4] = f2bf(x1.x); a[kc][5] = f2bf(x1.y);
        a[kc][6] = f2bf(x1.z); a[kc][7] = f2bf(x1.w);
    }
#pragma unroll
    for (int mp = 0; mp < NMP; ++mp) {
        float dv = dinv[mp * NNODES + rowbase + m];   // per x-row scale
#pragma unroll
        for (int nt = 0; nt < 4; ++nt) {
            const bf16x8* bp = (const bf16x8*)(wT + (size_t)(mp * D + nt * 16 + m) * D);
            bf16x8 b0 = bp[q];       // k = q*8 .. +7
            bf16x8 b1 = bp[4 + q];   // k = 32 + q*8 .. +7
            floatx4 acc = {0.f, 0.f, 0.f, 0.f};
            acc = __builtin_amdgcn_mfma_f32_16x16x32_bf16(b0, a[0], acc, 0, 0, 0);
            acc = __builtin_amdgcn_mfma_f32_16x16x32_bf16(b1, a[1], acc, 0, 0, 0);
            unsigned v0 = (unsigned)__half_as_ushort(__float2half(acc[0] * dv)) |
                          ((unsigned)__half_as_ushort(__float2half(acc[1] * dv)) << 16);
            unsigned v1 = (unsigned)__half_as_ushort(__float2half(acc[2] * dv)) |
                          ((unsigned)__half_as_ushort(__float2half(acc[3] * dv)) << 16);
            *(uint2*)(h + ((size_t)mp * NNODES + rowbase + m) * D + nt * 16 + q * 4) =
                make_uint2(v0, v1);
        }
    }
}

// ---------------- gather: 2 nodes/wave, 4 edge slots/node, depth-2 pipeline, pk_fma_f16 --------
// 32 lanes per node: g = edge slot (0..3), f = feature chunk (8 x 16B = 128B f16 row).
// Inner loop: 4 __hfma2 (v_pk_fma_f16) per 16B chunk instead of 8 unpack + 8 fma (16 -> 5 VALU).
__global__ __launch_bounds__(256) void gather_kernel(const int2* __restrict__ nodeoff,
                                                     const uint2* __restrict__ dense,
                                                     const unsigned short* __restrict__ h,
                                                     const float* __restrict__ dinv,
                                                     float* __restrict__ out) {
    const int tid = threadIdx.x;
    const int wave = tid >> 6, lane = tid & 63;
    const int sub = lane >> 5;     // node within wave (0..1)
    const int g = (lane >> 3) & 3; // edge slot (0..3)
    const int f = lane & 7;        // feature chunk (8 f16 = 16 B)
    const int w = blockIdx.x * 8 + wave * 2 + sub;   // NTOT = 8*37500
    int2 off = nodeoff[w];
    const int start = off.x, end = off.x + off.y;
    const uint4* hp = (const uint4*)h;               // h at ws offset 0: 128B-row aligned
    __half2 acc2[4];
    acc2[0] = __float2half2_rn(0.0f); acc2[1] = __float2half2_rn(0.0f);
    acc2[2] = __float2half2_rn(0.0f); acc2[3] = __float2half2_rn(0.0f);
    if (end > start) {
        const int last = end - 1;
        uint2 prA = dense[min(start + g, last)];
        uint2 prB = dense[min(start + 4 + g, last)];
        uint4 hvA = hp[(size_t)prA.x * 8 + f];
        for (int p = start; p < end; p += 4) {
            uint2 prC = dense[min(p + 8 + g, last)];
            uint4 hvB = hp[(size_t)prB.x * 8 + f];   // addr ready (record loaded 2 rounds ago)
            float wgt = (p + g < end) ? __uint_as_float(prA.y) : 0.0f;
            __half2 wp = __float2half2_rn(wgt);
            acc2[0] = __hfma2(u2h(hvA.x), wp, acc2[0]);
            acc2[1] = __hfma2(u2h(hvA.y), wp, acc2[1]);
            acc2[2] = __hfma2(u2h(hvA.z), wp, acc2[2]);
            acc2[3] = __hfma2(u2h(hvA.w), wp, acc2[3]);
            prA = prB; hvA = hvB; prB = prC;
        }
    }
    float acc[8];
    acc[0] = __low2float(acc2[0]); acc[1] = __high2float(acc2[0]);
    acc[2] = __low2float(acc2[1]); acc[3] = __high2float(acc2[1]);
    acc[4] = __low2float(acc2[2]); acc[5] = __high2float(acc2[2]);
    acc[6] = __low2float(acc2[3]); acc[7] = __high2float(acc2[3]);
#pragma unroll
    for (int j = 0; j < 8; ++j) {                   // reduce across 4 edge slots (f32)
        acc[j] += __shfl_xor(acc[j], 8);
        acc[j] += __shfl_xor(acc[j], 16);
    }
    float dv = dinv[w];
    if (g < 2) {
        float4 o = g ? make_float4(acc[4], acc[5], acc[6], acc[7])
                     : make_float4(acc[0], acc[1], acc[2], acc[3]);
        o.x = fmaxf(o.x * dv, 0.0f);
        o.y = fmaxf(o.y * dv, 0.0f);
        o.z = fmaxf(o.z * dv, 0.0f);
        o.w = fmaxf(o.w * dv, 0.0f);
        ((float4*)out)[(size_t)w * 16 + f * 2 + g] = o;   // 256 B contiguous per node
    }
}

extern "C" void kernel_launch(void* const* d_in, const int* in_sizes, int n_in,
                              void* d_out, int out_size, void* d_ws, size_t ws_size,
                              hipStream_t stream) {
    const float* x  = (const float*)d_in[0];   // [N, 64]
    const float* W  = (const float*)d_in[1];   // [3, 64, 64]
    const int*   ei = (const int*)d_in[2];     // [3, 2, E]
    const float* ew = (const float*)d_in[3];   // [3, E]
    float* out = (float*)d_out;                // [3, N, 64]

    // layout (bytes). A (25.65 MB) is dead after compact2; h (38.4 MB) overlays it.
    // NOTE: keep randomly-read buffers (h) 128B-aligned -- round-5's mod-64=24 xb cost +50% fetch.
    char* ws = (char*)d_ws;
    uint2* A           = (uint2*)(ws + 0);                     // 293*10944*8 = 25,652,736 B
    unsigned short* h  = (unsigned short*)(ws + 0);            // 38,400,000 B (overlays A)
    uint2* C           = (uint2*)(ws + 38400000);              // 25,652,736 B
    int2*  nodeoff     = (int2*)(ws + 64052736);               // 2,400,000 B
    float* dinv        = (float*)(ws + 66452736);              // 1,200,000 B
    unsigned short* wT = (unsigned short*)(ws + 67652736);     // 24,576 B
    int*   gcur        = (int*)(ws + 67677312);                // 1,172 B
    int*   ovcur       = (int*)(ws + 67678484);                // 4 B (adjacent to gcur)
    int*   ovf         = (int*)(ws + 67678488);                // 1,572,864 B -> ends ~69.25 MB

    hipMemsetAsync(gcur, 0, 1176, stream);     // gcur + ovcur

    split_kernel<<<dim3((NEDGES + T1 - 1) / T1, NMP), 512, 0, stream>>>(ei, ew, gcur,
                                                                        ovcur, ovf, A);
    compact2_kernel<<<NBIN, 256, 0, stream>>>(gcur, A, ovcur, ovf, C, nodeoff, dinv);
    prep_w_kernel<<<(NMP * D * D + 255) / 256, 256, 0, stream>>>(W, wT);
    gemm_kernel<<<(NNODES / 16 + 3) / 4, 256, 0, stream>>>(x, wT, dinv, h);
    gather_kernel<<<NTOT / 8, 256, 0, stream>>>(nodeoff, C, h, dinv, out);
}